// Round 1
// baseline (442.525 us; speedup 1.0000x reference)
//
#include <hip/hip_runtime.h>

#define NEG_SLOPE 0.2f
#define LRELU(x) ((x) > 0.0f ? (x) : NEG_SLOPE * (x))

// ---------------- GEMM: XH[M,256] = X[M,256] @ W[256,256] (f32) ----------------
__global__ __launch_bounds__(256) void gemm_kernel(const float* __restrict__ X,
                                                   const float* __restrict__ Wm,
                                                   float* __restrict__ XH, int M) {
  __shared__ float As[16][65];
  __shared__ float Bs[16][65];
  int tid = threadIdx.x;
  int tx = tid & 15, ty = tid >> 4;
  int m0 = blockIdx.x * 64;
  int n0 = blockIdx.y * 64;
  float acc[4][4] = {{0.f}};
  for (int k0 = 0; k0 < 256; k0 += 16) {
    // load A tile 64x16 (transposed into LDS)
    {
      int r = tid >> 2;           // 0..63 row in tile
      int kc = (tid & 3) << 2;    // 0,4,8,12
      float4 va = make_float4(0.f, 0.f, 0.f, 0.f);
      if (m0 + r < M)
        va = *reinterpret_cast<const float4*>(X + (size_t)(m0 + r) * 256 + k0 + kc);
      As[kc + 0][r] = va.x; As[kc + 1][r] = va.y;
      As[kc + 2][r] = va.z; As[kc + 3][r] = va.w;
    }
    // load B tile 16x64
    {
      int rb = tid >> 4;          // 0..15 k row
      int cb = (tid & 15) << 2;   // 0..60
      float4 vb = *reinterpret_cast<const float4*>(Wm + (size_t)(k0 + rb) * 256 + n0 + cb);
      Bs[rb][cb + 0] = vb.x; Bs[rb][cb + 1] = vb.y;
      Bs[rb][cb + 2] = vb.z; Bs[rb][cb + 3] = vb.w;
    }
    __syncthreads();
#pragma unroll
    for (int kk = 0; kk < 16; ++kk) {
      float a[4], b[4];
#pragma unroll
      for (int i = 0; i < 4; ++i) a[i] = As[kk][(ty << 2) + i];
#pragma unroll
      for (int j = 0; j < 4; ++j) b[j] = Bs[kk][(tx << 2) + j];
#pragma unroll
      for (int i = 0; i < 4; ++i)
#pragma unroll
        for (int j = 0; j < 4; ++j) acc[i][j] += a[i] * b[j];
    }
    __syncthreads();
  }
#pragma unroll
  for (int i = 0; i < 4; ++i) {
    int row = m0 + (ty << 2) + i;
    if (row < M) {
      float4 o = make_float4(acc[i][0], acc[i][1], acc[i][2], acc[i][3]);
      *reinterpret_cast<float4*>(XH + (size_t)row * 256 + n0 + (tx << 2)) = o;
    }
  }
}

// ------------- per-node attention dots: a_src[n][h], a_dst[n][h] -------------
// one wave per node; lane handles channels 4*lane..4*lane+3 (head = lane>>4)
__global__ __launch_bounds__(256) void node_att_kernel(const float* __restrict__ XH,
                                                       const float* __restrict__ att_src,
                                                       const float* __restrict__ att_dst,
                                                       float* __restrict__ a_src,
                                                       float* __restrict__ a_dst, int N) {
  int wid = threadIdx.x >> 6;
  int lane = threadIdx.x & 63;
  int node = blockIdx.x * 4 + wid;
  if (node >= N) return;
  float4 v = *reinterpret_cast<const float4*>(XH + (size_t)node * 256 + (lane << 2));
  float4 ws = reinterpret_cast<const float4*>(att_src)[lane];
  float4 wd = reinterpret_cast<const float4*>(att_dst)[lane];
  float ds = v.x * ws.x + v.y * ws.y + v.z * ws.z + v.w * ws.w;
  float dd = v.x * wd.x + v.y * wd.y + v.z * wd.z + v.w * wd.w;
  // reduce within each 16-lane group (one head)
  for (int off = 1; off < 16; off <<= 1) {
    ds += __shfl_xor(ds, off, 64);
    dd += __shfl_xor(dd, off, 64);
  }
  if ((lane & 15) == 0) {
    int h = lane >> 4;
    a_src[node * 4 + h] = ds;
    a_dst[node * 4 + h] = dd;
  }
}

// ------------------------------- CSR build -----------------------------------
__global__ void count_kernel(const int* __restrict__ ei, int* __restrict__ deg, int E) {
  int e = blockIdx.x * blockDim.x + threadIdx.x;
  if (e < E) atomicAdd(&deg[ei[E + e]], 1);
}

__global__ __launch_bounds__(1024) void scan_kernel(const int* __restrict__ deg,
                                                    int* __restrict__ row_start, int n) {
  __shared__ int buf[1024];
  __shared__ int carry_s;
  if (threadIdx.x == 0) carry_s = 0;
  __syncthreads();
  for (int base = 0; base < n; base += 1024) {
    int i = base + (int)threadIdx.x;
    int v = (i < n) ? deg[i] : 0;
    buf[threadIdx.x] = v;
    __syncthreads();
    int run = v;
    for (int off = 1; off < 1024; off <<= 1) {
      int t = 0;
      if ((int)threadIdx.x >= off) t = buf[threadIdx.x - off];
      __syncthreads();
      run += t;
      buf[threadIdx.x] = run;
      __syncthreads();
    }
    int carry = carry_s;
    if (i < n) row_start[i] = carry + run - v;  // exclusive
    __syncthreads();
    if (threadIdx.x == 1023) carry_s = carry + buf[1023];
    __syncthreads();
  }
  if (threadIdx.x == 0) row_start[n] = carry_s;
}

__global__ void fill_kernel(const int* __restrict__ ei, const int* __restrict__ row_start,
                            int* __restrict__ cursor, int* __restrict__ csr_src, int E) {
  int e = blockIdx.x * blockDim.x + threadIdx.x;
  if (e < E) {
    int d = ei[E + e];
    int slot = row_start[d] + atomicAdd(&cursor[d], 1);
    csr_src[slot] = ei[e];
  }
}

// -------------------- aggregation: one wave per dst node ---------------------
__global__ __launch_bounds__(256) void aggregate_kernel(
    const float* __restrict__ XH, const float* __restrict__ a_src,
    const float* __restrict__ a_dst, const int* __restrict__ row_start,
    const int* __restrict__ csr_src, const float* __restrict__ bias,
    float* __restrict__ out, int N) {
  int wid = threadIdx.x >> 6;
  int lane = threadIdx.x & 63;
  int node = blockIdx.x * 4 + wid;
  if (node >= N) return;

  float4 adi = reinterpret_cast<const float4*>(a_dst)[node];
  float4 asi = reinterpret_cast<const float4*>(a_src)[node];
  // self-loop logits per head
  float4 lself;
  lself.x = LRELU(asi.x + adi.x);
  lself.y = LRELU(asi.y + adi.y);
  lself.z = LRELU(asi.z + adi.z);
  lself.w = LRELU(asi.w + adi.w);

  int start = row_start[node];
  int end = row_start[node + 1];

  // phase 1: max over edges (init with self-loop)
  float4 m = lself;
  for (int p = start + lane; p < end; p += 64) {
    int s = csr_src[p];
    float4 as = reinterpret_cast<const float4*>(a_src)[s];
    float lx = LRELU(as.x + adi.x);
    float ly = LRELU(as.y + adi.y);
    float lz = LRELU(as.z + adi.z);
    float lw = LRELU(as.w + adi.w);
    m.x = fmaxf(m.x, lx); m.y = fmaxf(m.y, ly);
    m.z = fmaxf(m.z, lz); m.w = fmaxf(m.w, lw);
  }
  for (int off = 1; off < 64; off <<= 1) {
    m.x = fmaxf(m.x, __shfl_xor(m.x, off, 64));
    m.y = fmaxf(m.y, __shfl_xor(m.y, off, 64));
    m.z = fmaxf(m.z, __shfl_xor(m.z, off, 64));
    m.w = fmaxf(m.w, __shfl_xor(m.w, off, 64));
  }

  // phase 2: sum of exp
  float4 ssum = make_float4(0.f, 0.f, 0.f, 0.f);
  for (int p = start + lane; p < end; p += 64) {
    int s = csr_src[p];
    float4 as = reinterpret_cast<const float4*>(a_src)[s];
    ssum.x += __expf(LRELU(as.x + adi.x) - m.x);
    ssum.y += __expf(LRELU(as.y + adi.y) - m.y);
    ssum.z += __expf(LRELU(as.z + adi.z) - m.z);
    ssum.w += __expf(LRELU(as.w + adi.w) - m.w);
  }
  for (int off = 1; off < 64; off <<= 1) {
    ssum.x += __shfl_xor(ssum.x, off, 64);
    ssum.y += __shfl_xor(ssum.y, off, 64);
    ssum.z += __shfl_xor(ssum.z, off, 64);
    ssum.w += __shfl_xor(ssum.w, off, 64);
  }
  float4 es;
  es.x = __expf(lself.x - m.x); es.y = __expf(lself.y - m.y);
  es.z = __expf(lself.z - m.z); es.w = __expf(lself.w - m.w);
  ssum.x += es.x; ssum.y += es.y; ssum.z += es.z; ssum.w += es.w;

  // per-lane head selection (lane covers channels 4*lane..4*lane+3, head = lane>>4)
  int h = lane >> 4;
  float m_h   = (h == 0) ? m.x   : (h == 1) ? m.y   : (h == 2) ? m.z   : m.w;
  float ad_h  = (h == 0) ? adi.x : (h == 1) ? adi.y : (h == 2) ? adi.z : adi.w;
  float es_h  = (h == 0) ? es.x  : (h == 1) ? es.y  : (h == 2) ? es.z  : es.w;
  float ss_h  = (h == 0) ? ssum.x: (h == 1) ? ssum.y: (h == 2) ? ssum.z: ssum.w;

  // phase 3: weighted accumulate (self-loop first)
  float4 v = *reinterpret_cast<const float4*>(XH + (size_t)node * 256 + (lane << 2));
  float4 acc;
  acc.x = es_h * v.x; acc.y = es_h * v.y; acc.z = es_h * v.z; acc.w = es_h * v.w;
  for (int p = start; p < end; ++p) {
    int s = csr_src[p];
    float a = a_src[s * 4 + h] + ad_h;
    float w = __expf(LRELU(a) - m_h);
    float4 u = *reinterpret_cast<const float4*>(XH + (size_t)s * 256 + (lane << 2));
    acc.x += w * u.x; acc.y += w * u.y; acc.z += w * u.z; acc.w += w * u.w;
  }
  float inv = 1.0f / ss_h;
  float4 b = reinterpret_cast<const float4*>(bias)[lane];
  float4 o;
  o.x = acc.x * inv + b.x; o.y = acc.y * inv + b.y;
  o.z = acc.z * inv + b.z; o.w = acc.w * inv + b.w;
  *reinterpret_cast<float4*>(out + (size_t)node * 256 + (lane << 2)) = o;
}

extern "C" void kernel_launch(void* const* d_in, const int* in_sizes, int n_in,
                              void* d_out, int out_size, void* d_ws, size_t ws_size,
                              hipStream_t stream) {
  const float* x      = (const float*)d_in[0];
  const int*   ei     = (const int*)d_in[1];
  const float* Wm     = (const float*)d_in[2];
  const float* attS   = (const float*)d_in[3];
  const float* attD   = (const float*)d_in[4];
  const float* bias   = (const float*)d_in[5];
  float* out = (float*)d_out;

  const int N = in_sizes[0] / 256;
  const int E = in_sizes[1] / 2;

  char* w = (char*)d_ws;
  float* xh = (float*)w;        w += (size_t)N * 256 * 4;
  float* a_src = (float*)w;     w += (size_t)N * 4 * 4;
  float* a_dst = (float*)w;     w += (size_t)N * 4 * 4;
  int* deg = (int*)w;           w += (size_t)N * 4;
  int* cursor = (int*)w;        w += (size_t)N * 4;
  int* row_start = (int*)w;     w += ((size_t)(N + 1) * 4 + 15) / 16 * 16;
  int* csr_src = (int*)w;       w += (size_t)E * 4;

  // GEMM
  dim3 ggrid((N + 63) / 64, 4);
  gemm_kernel<<<ggrid, 256, 0, stream>>>(x, Wm, xh, N);
  // per-node attention dots
  node_att_kernel<<<(N + 3) / 4, 256, 0, stream>>>(xh, attS, attD, a_src, a_dst, N);
  // CSR build
  hipMemsetAsync(deg, 0, (size_t)2 * N * 4, stream);  // deg + cursor (adjacent)
  count_kernel<<<(E + 255) / 256, 256, 0, stream>>>(ei, deg, E);
  scan_kernel<<<1, 1024, 0, stream>>>(deg, row_start, N);
  fill_kernel<<<(E + 255) / 256, 256, 0, stream>>>(ei, row_start, cursor, csr_src, E);
  // aggregate
  aggregate_kernel<<<(N + 3) / 4, 256, 0, stream>>>(xh, a_src, a_dst, row_start,
                                                    csr_src, bias, out, N);
}

// Round 2
// 299.234 us; speedup vs baseline: 1.4789x; 1.4789x over previous
//
#include <hip/hip_runtime.h>

#define NEG_SLOPE 0.2f
#define LRELU(x) ((x) > 0.0f ? (x) : NEG_SLOPE * (x))

typedef short short8 __attribute__((ext_vector_type(8)));
typedef float f32x4v __attribute__((ext_vector_type(4)));

__device__ __forceinline__ unsigned short f2bf(float f) {
  unsigned int u = __float_as_uint(f);
  unsigned int r = (u + 0x7FFFu + ((u >> 16) & 1u)) >> 16;
  return (unsigned short)r;
}

__device__ __forceinline__ void gload_lds16(const void* g, void* l) {
  __builtin_amdgcn_global_load_lds(
      (const __attribute__((address_space(1))) unsigned int*)g,
      (__attribute__((address_space(3))) unsigned int*)l, 16, 0, 0);
}

// ------------- convert x (f32) -> bf16, zero-pad rows to Mp ------------------
__global__ __launch_bounds__(256) void convert_x(const float* __restrict__ X,
                                                 unsigned short* __restrict__ Xb,
                                                 int total, int valid) {
  int i = (blockIdx.x * 256 + threadIdx.x) * 4;
  if (i >= total) return;
  ushort4 w;
  if (i < valid) {
    float4 v = *reinterpret_cast<const float4*>(X + i);
    w.x = f2bf(v.x); w.y = f2bf(v.y); w.z = f2bf(v.z); w.w = f2bf(v.w);
  } else {
    w.x = w.y = w.z = w.w = 0;
  }
  *reinterpret_cast<ushort4*>(Xb + i) = w;
}

// ------------- convert W (f32, [K=256][256]) -> Wt bf16 ([n][k]) -------------
__global__ __launch_bounds__(256) void convert_wt(const float* __restrict__ W,
                                                  unsigned short* __restrict__ Wtb) {
  int k = threadIdx.x;
  int n = blockIdx.x;
  Wtb[n * 256 + k] = f2bf(W[k * 256 + n]);
}

// ---------------- MFMA GEMM: XH[Mp,256] = Xb[Mp,256] @ W --------------------
// 128x128 tile, BK=32, 4 waves, each wave 64x64 via 4x4 mfma_f32_16x16x32_bf16
__global__ __launch_bounds__(256) void gemm_mfma(const unsigned short* __restrict__ Xb,
                                                 const unsigned short* __restrict__ Wtb,
                                                 float* __restrict__ XH, int Mp) {
  __shared__ unsigned short lA[128 * 32];
  __shared__ unsigned short lB[128 * 32];
  const int tid = threadIdx.x;
  const int lane = tid & 63;
  const int wave = tid >> 6;
  const int m0 = blockIdx.x * 128;
  const int n0 = blockIdx.y * 128;
  const int wr = (wave >> 1) * 64;  // wave row offset in tile
  const int wc = (wave & 1) * 64;   // wave col offset in tile

  f32x4v acc[4][4];
#pragma unroll
  for (int i = 0; i < 4; ++i)
#pragma unroll
    for (int j = 0; j < 4; ++j) acc[i][j] = (f32x4v)(0.0f);

  // staging decode: thread covers linear bytes tid*16 (rows 0..63) and +4096 (rows 64..127)
  const int srow = tid >> 2;        // 0..63
  const int skb = (tid & 3) * 16;   // byte offset of 16B chunk within 64B row
  const char* XbC = (const char*)Xb;
  const char* WtC = (const char*)Wtb;
  char* lAc = (char*)&lA[0];
  char* lBc = (char*)&lB[0];
  const int ldsB0 = wave * 1024;    // wave-uniform dest base, issue 0
  const int lr = lane & 15;
  const int kq = (lane >> 4) * 16;  // byte offset of this lane's k-chunk within a row

  for (int k0 = 0; k0 < 256; k0 += 32) {
    const size_t kbyte = (size_t)k0 * 2 + skb;
    gload_lds16(XbC + (size_t)(m0 + srow) * 512 + kbyte, lAc + ldsB0);
    gload_lds16(XbC + (size_t)(m0 + srow + 64) * 512 + kbyte, lAc + ldsB0 + 4096);
    gload_lds16(WtC + (size_t)(n0 + srow) * 512 + kbyte, lBc + ldsB0);
    gload_lds16(WtC + (size_t)(n0 + srow + 64) * 512 + kbyte, lBc + ldsB0 + 4096);
    __syncthreads();

    short8 a[4], b[4];
#pragma unroll
    for (int i = 0; i < 4; ++i)
      a[i] = *reinterpret_cast<const short8*>(lAc + (wr + i * 16 + lr) * 64 + kq);
#pragma unroll
    for (int j = 0; j < 4; ++j)
      b[j] = *reinterpret_cast<const short8*>(lBc + (wc + j * 16 + lr) * 64 + kq);
#pragma unroll
    for (int i = 0; i < 4; ++i)
#pragma unroll
      for (int j = 0; j < 4; ++j)
        acc[i][j] = __builtin_amdgcn_mfma_f32_16x16x32_bf16(a[i], b[j], acc[i][j], 0, 0, 0);
    __syncthreads();
  }

  // epilogue: C/D layout col=lane&15, row=(lane>>4)*4+r
  const int rbase = m0 + wr + (lane >> 4) * 4;
#pragma unroll
  for (int i = 0; i < 4; ++i)
#pragma unroll
    for (int j = 0; j < 4; ++j) {
      int col = n0 + wc + j * 16 + lr;
#pragma unroll
      for (int r = 0; r < 4; ++r)
        XH[(size_t)(rbase + i * 16 + r) * 256 + col] = acc[i][j][r];
    }
}

// ------------- per-node attention dots: a_src[n][h], a_dst[n][h] -------------
__global__ __launch_bounds__(256) void node_att_kernel(const float* __restrict__ XH,
                                                       const float* __restrict__ att_src,
                                                       const float* __restrict__ att_dst,
                                                       float* __restrict__ a_src,
                                                       float* __restrict__ a_dst, int N) {
  int wid = threadIdx.x >> 6;
  int lane = threadIdx.x & 63;
  int node = blockIdx.x * 4 + wid;
  if (node >= N) return;
  float4 v = *reinterpret_cast<const float4*>(XH + (size_t)node * 256 + (lane << 2));
  float4 ws = reinterpret_cast<const float4*>(att_src)[lane];
  float4 wd = reinterpret_cast<const float4*>(att_dst)[lane];
  float ds = v.x * ws.x + v.y * ws.y + v.z * ws.z + v.w * ws.w;
  float dd = v.x * wd.x + v.y * wd.y + v.z * wd.z + v.w * wd.w;
  for (int off = 1; off < 16; off <<= 1) {
    ds += __shfl_xor(ds, off, 64);
    dd += __shfl_xor(dd, off, 64);
  }
  if ((lane & 15) == 0) {
    int h = lane >> 4;
    a_src[node * 4 + h] = ds;
    a_dst[node * 4 + h] = dd;
  }
}

// ------------------------------- CSR build -----------------------------------
__global__ void count_kernel(const int* __restrict__ ei, int* __restrict__ deg, int E) {
  int e = blockIdx.x * blockDim.x + threadIdx.x;
  if (e < E) atomicAdd(&deg[ei[E + e]], 1);
}

__global__ __launch_bounds__(1024) void scan1_kernel(const int* __restrict__ deg,
                                                     int* __restrict__ row_start,
                                                     int* __restrict__ bsum, int N) {
  __shared__ int buf[1024];
  int i = blockIdx.x * 1024 + (int)threadIdx.x;
  int v = (i < N) ? deg[i] : 0;
  buf[threadIdx.x] = v;
  __syncthreads();
  int run = v;
  for (int off = 1; off < 1024; off <<= 1) {
    int t = ((int)threadIdx.x >= off) ? buf[threadIdx.x - off] : 0;
    __syncthreads();
    run += t;
    buf[threadIdx.x] = run;
    __syncthreads();
  }
  if (i < N) row_start[i] = run - v;  // exclusive, pre-block-offset
  if (threadIdx.x == 1023) bsum[blockIdx.x] = run;
}

__global__ void scan2_kernel(int* __restrict__ bsum, int* __restrict__ row_start,
                             int nb, int N) {
  int acc = 0;
  for (int b = 0; b < nb; ++b) {
    int t = bsum[b];
    bsum[b] = acc;
    acc += t;
  }
  row_start[N] = acc;
}

__global__ __launch_bounds__(1024) void scan3_kernel(int* __restrict__ row_start,
                                                     const int* __restrict__ bsum, int N) {
  int i = blockIdx.x * 1024 + (int)threadIdx.x;
  if (i < N) row_start[i] += bsum[blockIdx.x];
}

__global__ void fill_kernel(const int* __restrict__ ei, const int* __restrict__ row_start,
                            int* __restrict__ cursor, int* __restrict__ csr_src, int E) {
  int e = blockIdx.x * blockDim.x + threadIdx.x;
  if (e < E) {
    int d = ei[E + e];
    int slot = row_start[d] + atomicAdd(&cursor[d], 1);
    csr_src[slot] = ei[e];
  }
}

// ---- softmax stats + per-edge alpha (one wave per dst node) -----------------
__global__ __launch_bounds__(256) void stats_kernel(
    const float* __restrict__ a_src, const float* __restrict__ a_dst,
    const int* __restrict__ row_start, const int* __restrict__ csr_src,
    float* __restrict__ alpha, float* __restrict__ self_alpha, int N) {
  int wid = threadIdx.x >> 6;
  int lane = threadIdx.x & 63;
  int node = blockIdx.x * 4 + wid;
  if (node >= N) return;

  float4 adi = reinterpret_cast<const float4*>(a_dst)[node];
  float4 asi = reinterpret_cast<const float4*>(a_src)[node];
  float4 lself;
  lself.x = LRELU(asi.x + adi.x);
  lself.y = LRELU(asi.y + adi.y);
  lself.z = LRELU(asi.z + adi.z);
  lself.w = LRELU(asi.w + adi.w);

  int start = row_start[node];
  int end = row_start[node + 1];

  float4 m = lself;
  for (int p = start + lane; p < end; p += 64) {
    int s = csr_src[p];
    float4 as = reinterpret_cast<const float4*>(a_src)[s];
    m.x = fmaxf(m.x, LRELU(as.x + adi.x));
    m.y = fmaxf(m.y, LRELU(as.y + adi.y));
    m.z = fmaxf(m.z, LRELU(as.z + adi.z));
    m.w = fmaxf(m.w, LRELU(as.w + adi.w));
  }
  for (int off = 1; off < 64; off <<= 1) {
    m.x = fmaxf(m.x, __shfl_xor(m.x, off, 64));
    m.y = fmaxf(m.y, __shfl_xor(m.y, off, 64));
    m.z = fmaxf(m.z, __shfl_xor(m.z, off, 64));
    m.w = fmaxf(m.w, __shfl_xor(m.w, off, 64));
  }

  float4 ssum = make_float4(0.f, 0.f, 0.f, 0.f);
  for (int p = start + lane; p < end; p += 64) {
    int s = csr_src[p];
    float4 as = reinterpret_cast<const float4*>(a_src)[s];
    ssum.x += __expf(LRELU(as.x + adi.x) - m.x);
    ssum.y += __expf(LRELU(as.y + adi.y) - m.y);
    ssum.z += __expf(LRELU(as.z + adi.z) - m.z);
    ssum.w += __expf(LRELU(as.w + adi.w) - m.w);
  }
  for (int off = 1; off < 64; off <<= 1) {
    ssum.x += __shfl_xor(ssum.x, off, 64);
    ssum.y += __shfl_xor(ssum.y, off, 64);
    ssum.z += __shfl_xor(ssum.z, off, 64);
    ssum.w += __shfl_xor(ssum.w, off, 64);
  }
  float4 es;
  es.x = __expf(lself.x - m.x);
  es.y = __expf(lself.y - m.y);
  es.z = __expf(lself.z - m.z);
  es.w = __expf(lself.w - m.w);
  ssum.x += es.x; ssum.y += es.y; ssum.z += es.z; ssum.w += es.w;

  float4 inv;
  inv.x = 1.0f / ssum.x; inv.y = 1.0f / ssum.y;
  inv.z = 1.0f / ssum.z; inv.w = 1.0f / ssum.w;

  for (int p = start + lane; p < end; p += 64) {
    int s = csr_src[p];
    float4 as = reinterpret_cast<const float4*>(a_src)[s];
    float4 al;
    al.x = __expf(LRELU(as.x + adi.x) - m.x) * inv.x;
    al.y = __expf(LRELU(as.y + adi.y) - m.y) * inv.y;
    al.z = __expf(LRELU(as.z + adi.z) - m.z) * inv.z;
    al.w = __expf(LRELU(as.w + adi.w) - m.w) * inv.w;
    *reinterpret_cast<float4*>(alpha + (size_t)p * 4) = al;
  }
  if (lane == 0) {
    float4 sa;
    sa.x = es.x * inv.x; sa.y = es.y * inv.y;
    sa.z = es.z * inv.z; sa.w = es.w * inv.w;
    *reinterpret_cast<float4*>(self_alpha + (size_t)node * 4) = sa;
  }
}

// -------------------- aggregation: one wave per dst node ---------------------
__global__ __launch_bounds__(256) void aggregate_kernel(
    const float* __restrict__ XH, const float* __restrict__ alpha,
    const float* __restrict__ self_alpha, const int* __restrict__ row_start,
    const int* __restrict__ csr_src, const float* __restrict__ bias,
    float* __restrict__ out, int N) {
  int wid = threadIdx.x >> 6;
  int lane = threadIdx.x & 63;
  int node = blockIdx.x * 4 + wid;
  if (node >= N) return;

  int h = lane >> 4;
  int c = lane << 2;
  int start = row_start[node];
  int end = row_start[node + 1];

  float sw = self_alpha[node * 4 + h];
  float4 v = *reinterpret_cast<const float4*>(XH + (size_t)node * 256 + c);
  float4 acc;
  acc.x = sw * v.x; acc.y = sw * v.y; acc.z = sw * v.z; acc.w = sw * v.w;

  int p = start;
  for (; p + 2 <= end; p += 2) {
    int s0 = csr_src[p];
    int s1 = csr_src[p + 1];
    float w0 = alpha[(size_t)p * 4 + h];
    float w1 = alpha[(size_t)(p + 1) * 4 + h];
    float4 u0 = *reinterpret_cast<const float4*>(XH + (size_t)s0 * 256 + c);
    float4 u1 = *reinterpret_cast<const float4*>(XH + (size_t)s1 * 256 + c);
    acc.x += w0 * u0.x; acc.y += w0 * u0.y; acc.z += w0 * u0.z; acc.w += w0 * u0.w;
    acc.x += w1 * u1.x; acc.y += w1 * u1.y; acc.z += w1 * u1.z; acc.w += w1 * u1.w;
  }
  if (p < end) {
    int s0 = csr_src[p];
    float w0 = alpha[(size_t)p * 4 + h];
    float4 u0 = *reinterpret_cast<const float4*>(XH + (size_t)s0 * 256 + c);
    acc.x += w0 * u0.x; acc.y += w0 * u0.y; acc.z += w0 * u0.z; acc.w += w0 * u0.w;
  }

  float4 b = reinterpret_cast<const float4*>(bias)[lane];
  float4 o;
  o.x = acc.x + b.x; o.y = acc.y + b.y; o.z = acc.z + b.z; o.w = acc.w + b.w;
  *reinterpret_cast<float4*>(out + (size_t)node * 256 + c) = o;
}

extern "C" void kernel_launch(void* const* d_in, const int* in_sizes, int n_in,
                              void* d_out, int out_size, void* d_ws, size_t ws_size,
                              hipStream_t stream) {
  const float* x    = (const float*)d_in[0];
  const int*   ei   = (const int*)d_in[1];
  const float* Wm   = (const float*)d_in[2];
  const float* bias = (const float*)d_in[5];
  const float* attS = (const float*)d_in[3];
  const float* attD = (const float*)d_in[4];
  float* out = (float*)d_out;

  const int N = in_sizes[0] / 256;
  const int E = in_sizes[1] / 2;
  const int Mp = (N + 127) / 128 * 128;
  const int nb = (N + 1023) / 1024;

  char* w = (char*)d_ws;
  float* xh = (float*)w;              w += (size_t)Mp * 256 * 4;
  unsigned short* Xb = (unsigned short*)w;  w += (size_t)Mp * 256 * 2;
  unsigned short* Wtb = (unsigned short*)w; w += (size_t)256 * 256 * 2;
  float* a_src = (float*)w;           w += (size_t)N * 4 * 4;
  float* a_dst = (float*)w;           w += (size_t)N * 4 * 4;
  float* self_alpha = (float*)w;      w += (size_t)N * 4 * 4;
  int* deg = (int*)w;                 w += (size_t)N * 4;
  int* cursor = (int*)w;              w += (size_t)N * 4;
  int* row_start = (int*)w;           w += ((size_t)(N + 1) * 4 + 255) / 256 * 256;
  int* bsum = (int*)w;                w += ((size_t)nb * 4 + 255) / 256 * 256;
  int* csr_src = (int*)w;             w += (size_t)E * 4;
  float* alpha = (float*)w;           w += (size_t)E * 16;

  // convert inputs to bf16 (x padded with zero rows to Mp)
  convert_x<<<(Mp * 256 / 4 + 255) / 256, 256, 0, stream>>>(x, Xb, Mp * 256, N * 256);
  convert_wt<<<256, 256, 0, stream>>>(Wm, Wtb);

  // MFMA GEMM
  dim3 ggrid(Mp / 128, 2);
  gemm_mfma<<<ggrid, 256, 0, stream>>>(Xb, Wtb, xh, Mp);

  // per-node attention dots
  node_att_kernel<<<(N + 3) / 4, 256, 0, stream>>>(xh, attS, attD, a_src, a_dst, N);

  // CSR build
  hipMemsetAsync(deg, 0, (size_t)2 * N * 4, stream);  // deg + cursor (adjacent)
  count_kernel<<<(E + 255) / 256, 256, 0, stream>>>(ei, deg, E);
  scan1_kernel<<<nb, 1024, 0, stream>>>(deg, row_start, bsum, N);
  scan2_kernel<<<1, 1, 0, stream>>>(bsum, row_start, nb, N);
  scan3_kernel<<<nb, 1024, 0, stream>>>(row_start, bsum, N);
  fill_kernel<<<(E + 255) / 256, 256, 0, stream>>>(ei, row_start, cursor, csr_src, E);

  // softmax stats + per-edge alpha
  stats_kernel<<<(N + 3) / 4, 256, 0, stream>>>(a_src, a_dst, row_start, csr_src,
                                                alpha, self_alpha, N);
  // aggregate
  aggregate_kernel<<<(N + 3) / 4, 256, 0, stream>>>(xh, alpha, self_alpha, row_start,
                                                    csr_src, bias, out, N);
}

// Round 3
// 214.385 us; speedup vs baseline: 2.0642x; 1.3958x over previous
//
#include <hip/hip_runtime.h>

#define NEG_SLOPE 0.2f
#define LRELU(x) ((x) > 0.0f ? (x) : NEG_SLOPE * (x))

typedef short short8 __attribute__((ext_vector_type(8)));
typedef float f32x4v __attribute__((ext_vector_type(4)));

__device__ __forceinline__ unsigned short f2bf(float f) {
  unsigned int u = __float_as_uint(f);
  unsigned int r = (u + 0x7FFFu + ((u >> 16) & 1u)) >> 16;
  return (unsigned short)r;
}

__device__ __forceinline__ float bf2f(unsigned short u) {
  return __uint_as_float(((unsigned int)u) << 16);
}

__device__ __forceinline__ void gload_lds16(const void* g, void* l) {
  __builtin_amdgcn_global_load_lds(
      (const __attribute__((address_space(1))) unsigned int*)g,
      (__attribute__((address_space(3))) unsigned int*)l, 16, 0, 0);
}

// ------------- convert x (f32) -> bf16, zero-pad rows to Mp ------------------
__global__ __launch_bounds__(256) void convert_x(const float* __restrict__ X,
                                                 unsigned short* __restrict__ Xb,
                                                 int total, int valid) {
  int i = (blockIdx.x * 256 + threadIdx.x) * 4;
  if (i >= total) return;
  ushort4 w;
  if (i < valid) {
    float4 v = *reinterpret_cast<const float4*>(X + i);
    w.x = f2bf(v.x); w.y = f2bf(v.y); w.z = f2bf(v.z); w.w = f2bf(v.w);
  } else {
    w.x = w.y = w.z = w.w = 0;
  }
  *reinterpret_cast<ushort4*>(Xb + i) = w;
}

// ------------- convert W (f32, [K=256][256]) -> Wt bf16 ([n][k]) -------------
__global__ __launch_bounds__(256) void convert_wt(const float* __restrict__ W,
                                                  unsigned short* __restrict__ Wtb) {
  int k = threadIdx.x;
  int n = blockIdx.x;
  Wtb[n * 256 + k] = f2bf(W[k * 256 + n]);
}

// ---------------- MFMA GEMM + fused attention dots ---------------------------
// XHb[Mp,256](bf16) = Xb @ W ; a_src[n][h], a_dst[n][h] from f32 accumulators.
// 128x128 tile, BK=32, 4 waves, each wave 64x64 via 4x4 mfma_f32_16x16x32_bf16.
// Each wave's 64 columns lie entirely within one head -> dot completes in-wave.
__global__ __launch_bounds__(256) void gemm_mfma(
    const unsigned short* __restrict__ Xb, const unsigned short* __restrict__ Wtb,
    const float* __restrict__ attS, const float* __restrict__ attD,
    unsigned short* __restrict__ XHb, float* __restrict__ a_src,
    float* __restrict__ a_dst, int Mp, int N) {
  __shared__ unsigned short lA[128 * 32];
  __shared__ unsigned short lB[128 * 32];
  const int tid = threadIdx.x;
  const int lane = tid & 63;
  const int wave = tid >> 6;
  const int m0 = blockIdx.x * 128;
  const int n0 = blockIdx.y * 128;
  const int wr = (wave >> 1) * 64;
  const int wc = (wave & 1) * 64;

  f32x4v acc[4][4];
#pragma unroll
  for (int i = 0; i < 4; ++i)
#pragma unroll
    for (int j = 0; j < 4; ++j) acc[i][j] = (f32x4v)(0.0f);

  const int srow = tid >> 2;
  const int skb = (tid & 3) * 16;
  const char* XbC = (const char*)Xb;
  const char* WtC = (const char*)Wtb;
  char* lAc = (char*)&lA[0];
  char* lBc = (char*)&lB[0];
  const int ldsB0 = wave * 1024;
  const int lr = lane & 15;
  const int hq = lane >> 4;
  const int kq = hq * 16;

  for (int k0 = 0; k0 < 256; k0 += 32) {
    const size_t kbyte = (size_t)k0 * 2 + skb;
    gload_lds16(XbC + (size_t)(m0 + srow) * 512 + kbyte, lAc + ldsB0);
    gload_lds16(XbC + (size_t)(m0 + srow + 64) * 512 + kbyte, lAc + ldsB0 + 4096);
    gload_lds16(WtC + (size_t)(n0 + srow) * 512 + kbyte, lBc + ldsB0);
    gload_lds16(WtC + (size_t)(n0 + srow + 64) * 512 + kbyte, lBc + ldsB0 + 4096);
    __syncthreads();

    short8 a[4], b[4];
#pragma unroll
    for (int i = 0; i < 4; ++i)
      a[i] = *reinterpret_cast<const short8*>(lAc + (wr + i * 16 + lr) * 64 + kq);
#pragma unroll
    for (int j = 0; j < 4; ++j)
      b[j] = *reinterpret_cast<const short8*>(lBc + (wc + j * 16 + lr) * 64 + kq);
#pragma unroll
    for (int i = 0; i < 4; ++i)
#pragma unroll
      for (int j = 0; j < 4; ++j)
        acc[i][j] = __builtin_amdgcn_mfma_f32_16x16x32_bf16(a[i], b[j], acc[i][j], 0, 0, 0);
    __syncthreads();
  }

  // ---- epilogue ----
  // C/D layout: col = n0+wc+j*16+(lane&15), row = m0+wr+(lane>>4)*4 + i*16 + r
  const int h = (n0 + wc) >> 6;  // this wave's head (cols are 64-aligned span)
  float ws_[4], wd_[4];
#pragma unroll
  for (int j = 0; j < 4; ++j) {
    ws_[j] = attS[h * 64 + j * 16 + lr];
    wd_[j] = attD[h * 64 + j * 16 + lr];
  }
  const int rbase = m0 + wr + hq * 4;

#pragma unroll
  for (int i = 0; i < 4; ++i) {
#pragma unroll
    for (int r = 0; r < 4; ++r) {
      float ps = 0.f, pd = 0.f;
#pragma unroll
      for (int j = 0; j < 4; ++j) {
        ps += acc[i][j][r] * ws_[j];
        pd += acc[i][j][r] * wd_[j];
      }
#pragma unroll
      for (int off = 1; off < 16; off <<= 1) {
        ps += __shfl_xor(ps, off, 64);
        pd += __shfl_xor(pd, off, 64);
      }
      int row = rbase + i * 16 + r;
      if (lr == 0 && row < N) {
        a_src[row * 4 + h] = ps;
        a_dst[row * 4 + h] = pd;
      }
    }
  }

  // bf16 store of xh
#pragma unroll
  for (int i = 0; i < 4; ++i)
#pragma unroll
    for (int j = 0; j < 4; ++j) {
      int col = n0 + wc + j * 16 + lr;
#pragma unroll
      for (int r = 0; r < 4; ++r)
        XHb[(size_t)(rbase + i * 16 + r) * 256 + col] = f2bf(acc[i][j][r]);
    }
}

// ------------------------------- CSR build -----------------------------------
__global__ void count_kernel(const int* __restrict__ ei, int* __restrict__ deg, int E) {
  int e = blockIdx.x * blockDim.x + threadIdx.x;
  if (e < E) atomicAdd(&deg[ei[E + e]], 1);
}

__global__ __launch_bounds__(1024) void scan1_kernel(const int* __restrict__ deg,
                                                     int* __restrict__ row_start,
                                                     int* __restrict__ bsum, int N) {
  __shared__ int buf[1024];
  int i = blockIdx.x * 1024 + (int)threadIdx.x;
  int v = (i < N) ? deg[i] : 0;
  buf[threadIdx.x] = v;
  __syncthreads();
  int run = v;
  for (int off = 1; off < 1024; off <<= 1) {
    int t = ((int)threadIdx.x >= off) ? buf[threadIdx.x - off] : 0;
    __syncthreads();
    run += t;
    buf[threadIdx.x] = run;
    __syncthreads();
  }
  if (i < N) row_start[i] = run - v;  // exclusive, pre-block-offset
  if (threadIdx.x == 1023) bsum[blockIdx.x] = run;
}

__global__ void scan2_kernel(int* __restrict__ bsum, int* __restrict__ row_start,
                             int nb, int N) {
  int acc = 0;
  for (int b = 0; b < nb; ++b) {
    int t = bsum[b];
    bsum[b] = acc;
    acc += t;
  }
  row_start[N] = acc;
}

__global__ __launch_bounds__(1024) void scan3_kernel(int* __restrict__ row_start,
                                                     const int* __restrict__ bsum, int N) {
  int i = blockIdx.x * 1024 + (int)threadIdx.x;
  if (i < N) row_start[i] += bsum[blockIdx.x];
}

__global__ void fill_kernel(const int* __restrict__ ei, const int* __restrict__ row_start,
                            int* __restrict__ cursor, int* __restrict__ csr_src, int E) {
  int e = blockIdx.x * blockDim.x + threadIdx.x;
  if (e < E) {
    int d = ei[E + e];
    int slot = row_start[d] + atomicAdd(&cursor[d], 1);
    csr_src[slot] = ei[e];
  }
}

// ---- fused softmax + aggregation: one wave per dst node ---------------------
__global__ __launch_bounds__(256) void gat_agg(
    const unsigned short* __restrict__ XHb, const float* __restrict__ a_src,
    const float* __restrict__ a_dst, const int* __restrict__ row_start,
    const int* __restrict__ csr_src, const float* __restrict__ bias,
    float* __restrict__ out, int N) {
  int wid = threadIdx.x >> 6;
  int lane = threadIdx.x & 63;
  int node = blockIdx.x * 4 + wid;
  if (node >= N) return;

  float4 adi = reinterpret_cast<const float4*>(a_dst)[node];
  float4 asi = reinterpret_cast<const float4*>(a_src)[node];
  float4 lself;
  lself.x = LRELU(asi.x + adi.x);
  lself.y = LRELU(asi.y + adi.y);
  lself.z = LRELU(asi.z + adi.z);
  lself.w = LRELU(asi.w + adi.w);

  int start = row_start[node];
  int end = row_start[node + 1];

  // phase 1: max (a_src is 800KB -> L2-resident gathers)
  float4 m = lself;
  for (int p = start + lane; p < end; p += 64) {
    int s = csr_src[p];
    float4 as = reinterpret_cast<const float4*>(a_src)[s];
    m.x = fmaxf(m.x, LRELU(as.x + adi.x));
    m.y = fmaxf(m.y, LRELU(as.y + adi.y));
    m.z = fmaxf(m.z, LRELU(as.z + adi.z));
    m.w = fmaxf(m.w, LRELU(as.w + adi.w));
  }
  for (int off = 1; off < 64; off <<= 1) {
    m.x = fmaxf(m.x, __shfl_xor(m.x, off, 64));
    m.y = fmaxf(m.y, __shfl_xor(m.y, off, 64));
    m.z = fmaxf(m.z, __shfl_xor(m.z, off, 64));
    m.w = fmaxf(m.w, __shfl_xor(m.w, off, 64));
  }

  // phase 2: sum of exp
  float4 ssum = make_float4(0.f, 0.f, 0.f, 0.f);
  for (int p = start + lane; p < end; p += 64) {
    int s = csr_src[p];
    float4 as = reinterpret_cast<const float4*>(a_src)[s];
    ssum.x += __expf(LRELU(as.x + adi.x) - m.x);
    ssum.y += __expf(LRELU(as.y + adi.y) - m.y);
    ssum.z += __expf(LRELU(as.z + adi.z) - m.z);
    ssum.w += __expf(LRELU(as.w + adi.w) - m.w);
  }
  for (int off = 1; off < 64; off <<= 1) {
    ssum.x += __shfl_xor(ssum.x, off, 64);
    ssum.y += __shfl_xor(ssum.y, off, 64);
    ssum.z += __shfl_xor(ssum.z, off, 64);
    ssum.w += __shfl_xor(ssum.w, off, 64);
  }
  float4 es;
  es.x = __expf(lself.x - m.x);
  es.y = __expf(lself.y - m.y);
  es.z = __expf(lself.z - m.z);
  es.w = __expf(lself.w - m.w);
  ssum.x += es.x; ssum.y += es.y; ssum.z += es.z; ssum.w += es.w;

  // per-lane head selection (lane covers channels 4*lane..4*lane+3)
  int h = lane >> 4;
  float m_h  = (h == 0) ? m.x   : (h == 1) ? m.y   : (h == 2) ? m.z   : m.w;
  float ad_h = (h == 0) ? adi.x : (h == 1) ? adi.y : (h == 2) ? adi.z : adi.w;
  float es_h = (h == 0) ? es.x  : (h == 1) ? es.y  : (h == 2) ? es.z  : es.w;
  float ss_h = (h == 0) ? ssum.x: (h == 1) ? ssum.y: (h == 2) ? ssum.z: ssum.w;

  // phase 3: weighted accumulate over bf16 rows (8B/lane gathers)
  ushort4 sv = *reinterpret_cast<const ushort4*>(XHb + (size_t)node * 256 + (lane << 2));
  float4 acc;
  acc.x = es_h * bf2f(sv.x); acc.y = es_h * bf2f(sv.y);
  acc.z = es_h * bf2f(sv.z); acc.w = es_h * bf2f(sv.w);

  int p = start;
  for (; p + 2 <= end; p += 2) {
    int s0 = csr_src[p];
    int s1 = csr_src[p + 1];
    float w0 = __expf(LRELU(a_src[s0 * 4 + h] + ad_h) - m_h);
    float w1 = __expf(LRELU(a_src[s1 * 4 + h] + ad_h) - m_h);
    ushort4 u0 = *reinterpret_cast<const ushort4*>(XHb + (size_t)s0 * 256 + (lane << 2));
    ushort4 u1 = *reinterpret_cast<const ushort4*>(XHb + (size_t)s1 * 256 + (lane << 2));
    acc.x += w0 * bf2f(u0.x); acc.y += w0 * bf2f(u0.y);
    acc.z += w0 * bf2f(u0.z); acc.w += w0 * bf2f(u0.w);
    acc.x += w1 * bf2f(u1.x); acc.y += w1 * bf2f(u1.y);
    acc.z += w1 * bf2f(u1.z); acc.w += w1 * bf2f(u1.w);
  }
  if (p < end) {
    int s0 = csr_src[p];
    float w0 = __expf(LRELU(a_src[s0 * 4 + h] + ad_h) - m_h);
    ushort4 u0 = *reinterpret_cast<const ushort4*>(XHb + (size_t)s0 * 256 + (lane << 2));
    acc.x += w0 * bf2f(u0.x); acc.y += w0 * bf2f(u0.y);
    acc.z += w0 * bf2f(u0.z); acc.w += w0 * bf2f(u0.w);
  }

  float inv = 1.0f / ss_h;
  float4 b = reinterpret_cast<const float4*>(bias)[lane];
  float4 o;
  o.x = acc.x * inv + b.x; o.y = acc.y * inv + b.y;
  o.z = acc.z * inv + b.z; o.w = acc.w * inv + b.w;
  *reinterpret_cast<float4*>(out + (size_t)node * 256 + (lane << 2)) = o;
}

extern "C" void kernel_launch(void* const* d_in, const int* in_sizes, int n_in,
                              void* d_out, int out_size, void* d_ws, size_t ws_size,
                              hipStream_t stream) {
  const float* x    = (const float*)d_in[0];
  const int*   ei   = (const int*)d_in[1];
  const float* Wm   = (const float*)d_in[2];
  const float* attS = (const float*)d_in[3];
  const float* attD = (const float*)d_in[4];
  const float* bias = (const float*)d_in[5];
  float* out = (float*)d_out;

  const int N = in_sizes[0] / 256;
  const int E = in_sizes[1] / 2;
  const int Mp = (N + 127) / 128 * 128;
  const int nb = (N + 1023) / 1024;

  char* w = (char*)d_ws;
  unsigned short* XHb = (unsigned short*)w;  w += (size_t)Mp * 256 * 2;
  unsigned short* Xb  = (unsigned short*)w;  w += (size_t)Mp * 256 * 2;
  unsigned short* Wtb = (unsigned short*)w;  w += (size_t)256 * 256 * 2;
  float* a_src = (float*)w;                  w += (size_t)N * 4 * 4;
  float* a_dst = (float*)w;                  w += (size_t)N * 4 * 4;
  int* deg = (int*)w;                        w += (size_t)N * 4;
  int* cursor = (int*)w;                     w += (size_t)N * 4;
  int* row_start = (int*)w;                  w += ((size_t)(N + 1) * 4 + 255) / 256 * 256;
  int* bsum = (int*)w;                       w += ((size_t)nb * 4 + 255) / 256 * 256;
  int* csr_src = (int*)w;                    w += (size_t)E * 4;

  // convert inputs to bf16 (x padded with zero rows to Mp)
  convert_x<<<(Mp * 256 / 4 + 255) / 256, 256, 0, stream>>>(x, Xb, Mp * 256, N * 256);
  convert_wt<<<256, 256, 0, stream>>>(Wm, Wtb);

  // MFMA GEMM with fused attention dots + bf16 xh output
  dim3 ggrid(Mp / 128, 2);
  gemm_mfma<<<ggrid, 256, 0, stream>>>(Xb, Wtb, attS, attD, XHb, a_src, a_dst, Mp, N);

  // CSR build
  hipMemsetAsync(deg, 0, (size_t)2 * N * 4, stream);  // deg + cursor (adjacent)
  count_kernel<<<(E + 255) / 256, 256, 0, stream>>>(ei, deg, E);
  scan1_kernel<<<nb, 1024, 0, stream>>>(deg, row_start, bsum, N);
  scan2_kernel<<<1, 1, 0, stream>>>(bsum, row_start, nb, N);
  scan3_kernel<<<nb, 1024, 0, stream>>>(row_start, bsum, N);
  fill_kernel<<<(E + 255) / 256, 256, 0, stream>>>(ei, row_start, cursor, csr_src, E);

  // fused softmax + aggregate
  gat_agg<<<(N + 3) / 4, 256, 0, stream>>>(XHb, a_src, a_dst, row_start, csr_src,
                                           bias, out, N);
}

// Round 4
// 198.536 us; speedup vs baseline: 2.2289x; 1.0798x over previous
//
#include <hip/hip_runtime.h>

#define NEG_SLOPE 0.2f
#define LRELU(x) ((x) > 0.0f ? (x) : NEG_SLOPE * (x))

typedef short short8 __attribute__((ext_vector_type(8)));
typedef float f32x4v __attribute__((ext_vector_type(4)));

__device__ __forceinline__ unsigned short f2bf(float f) {
  unsigned int u = __float_as_uint(f);
  unsigned int r = (u + 0x7FFFu + ((u >> 16) & 1u)) >> 16;
  return (unsigned short)r;
}

__device__ __forceinline__ float bf2f(unsigned short u) {
  return __uint_as_float(((unsigned int)u) << 16);
}

__device__ __forceinline__ void gload_lds16(const void* g, void* l) {
  __builtin_amdgcn_global_load_lds(
      (const __attribute__((address_space(1))) unsigned int*)g,
      (__attribute__((address_space(3))) unsigned int*)l, 16, 0, 0);
}

// ------------- convert x (f32) -> bf16, zero-pad rows to Mp ------------------
__global__ __launch_bounds__(256) void convert_x(const float* __restrict__ X,
                                                 unsigned short* __restrict__ Xb,
                                                 int total, int valid) {
  int i = (blockIdx.x * 256 + threadIdx.x) * 4;
  if (i >= total) return;
  ushort4 w;
  if (i < valid) {
    float4 v = *reinterpret_cast<const float4*>(X + i);
    w.x = f2bf(v.x); w.y = f2bf(v.y); w.z = f2bf(v.z); w.w = f2bf(v.w);
  } else {
    w.x = w.y = w.z = w.w = 0;
  }
  *reinterpret_cast<ushort4*>(Xb + i) = w;
}

// ------------- convert W (f32, [K=256][256]) -> Wt bf16 ([n][k]) -------------
__global__ __launch_bounds__(256) void convert_wt(const float* __restrict__ W,
                                                  unsigned short* __restrict__ Wtb) {
  int k = threadIdx.x;
  int n = blockIdx.x;
  Wtb[n * 256 + k] = f2bf(W[k * 256 + n]);
}

// ---------------- MFMA GEMM + fused attention dots ---------------------------
// XHb[Mp,256](bf16) = Xb @ W ; a_src[n][h], a_dst[n][h] from f32 accumulators.
// 128x128 tile, BK=32, 4 waves, each wave 64x64 via 4x4 mfma_f32_16x16x32_bf16.
__global__ __launch_bounds__(256) void gemm_mfma(
    const unsigned short* __restrict__ Xb, const unsigned short* __restrict__ Wtb,
    const float* __restrict__ attS, const float* __restrict__ attD,
    unsigned short* __restrict__ XHb, float* __restrict__ a_src,
    float* __restrict__ a_dst, int Mp, int N) {
  __shared__ unsigned short lA[128 * 32];
  __shared__ unsigned short lB[128 * 32];
  const int tid = threadIdx.x;
  const int lane = tid & 63;
  const int wave = tid >> 6;
  const int m0 = blockIdx.x * 128;
  const int n0 = blockIdx.y * 128;
  const int wr = (wave >> 1) * 64;
  const int wc = (wave & 1) * 64;

  f32x4v acc[4][4];
#pragma unroll
  for (int i = 0; i < 4; ++i)
#pragma unroll
    for (int j = 0; j < 4; ++j) acc[i][j] = (f32x4v)(0.0f);

  const int srow = tid >> 2;
  const int skb = (tid & 3) * 16;
  const char* XbC = (const char*)Xb;
  const char* WtC = (const char*)Wtb;
  char* lAc = (char*)&lA[0];
  char* lBc = (char*)&lB[0];
  const int ldsB0 = wave * 1024;
  const int lr = lane & 15;
  const int hq = lane >> 4;
  const int kq = hq * 16;

  for (int k0 = 0; k0 < 256; k0 += 32) {
    const size_t kbyte = (size_t)k0 * 2 + skb;
    gload_lds16(XbC + (size_t)(m0 + srow) * 512 + kbyte, lAc + ldsB0);
    gload_lds16(XbC + (size_t)(m0 + srow + 64) * 512 + kbyte, lAc + ldsB0 + 4096);
    gload_lds16(WtC + (size_t)(n0 + srow) * 512 + kbyte, lBc + ldsB0);
    gload_lds16(WtC + (size_t)(n0 + srow + 64) * 512 + kbyte, lBc + ldsB0 + 4096);
    __syncthreads();

    short8 a[4], b[4];
#pragma unroll
    for (int i = 0; i < 4; ++i)
      a[i] = *reinterpret_cast<const short8*>(lAc + (wr + i * 16 + lr) * 64 + kq);
#pragma unroll
    for (int j = 0; j < 4; ++j)
      b[j] = *reinterpret_cast<const short8*>(lBc + (wc + j * 16 + lr) * 64 + kq);
#pragma unroll
    for (int i = 0; i < 4; ++i)
#pragma unroll
      for (int j = 0; j < 4; ++j)
        acc[i][j] = __builtin_amdgcn_mfma_f32_16x16x32_bf16(a[i], b[j], acc[i][j], 0, 0, 0);
    __syncthreads();
  }

  // ---- epilogue ----
  const int h = (n0 + wc) >> 6;  // this wave's head (64-aligned col span)
  float ws_[4], wd_[4];
#pragma unroll
  for (int j = 0; j < 4; ++j) {
    ws_[j] = attS[h * 64 + j * 16 + lr];
    wd_[j] = attD[h * 64 + j * 16 + lr];
  }
  const int rbase = m0 + wr + hq * 4;

#pragma unroll
  for (int i = 0; i < 4; ++i) {
#pragma unroll
    for (int r = 0; r < 4; ++r) {
      float ps = 0.f, pd = 0.f;
#pragma unroll
      for (int j = 0; j < 4; ++j) {
        ps += acc[i][j][r] * ws_[j];
        pd += acc[i][j][r] * wd_[j];
      }
#pragma unroll
      for (int off = 1; off < 16; off <<= 1) {
        ps += __shfl_xor(ps, off, 64);
        pd += __shfl_xor(pd, off, 64);
      }
      int row = rbase + i * 16 + r;
      if (lr == 0 && row < N) {
        a_src[row * 4 + h] = ps;
        a_dst[row * 4 + h] = pd;
      }
    }
  }

#pragma unroll
  for (int i = 0; i < 4; ++i)
#pragma unroll
    for (int j = 0; j < 4; ++j) {
      int col = n0 + wc + j * 16 + lr;
#pragma unroll
      for (int r = 0; r < 4; ++r)
        XHb[(size_t)(rbase + i * 16 + r) * 256 + col] = f2bf(acc[i][j][r]);
    }
}

// ------------------------------- CSR build -----------------------------------
__global__ void count_kernel(const int* __restrict__ ei, int* __restrict__ deg, int E) {
  int e = blockIdx.x * blockDim.x + threadIdx.x;
  if (e < E) atomicAdd(&deg[ei[E + e]], 1);
}

__global__ __launch_bounds__(1024) void scan1_kernel(const int* __restrict__ deg,
                                                     int* __restrict__ row_start,
                                                     int* __restrict__ bsum, int N) {
  __shared__ int buf[1024];
  int i = blockIdx.x * 1024 + (int)threadIdx.x;
  int v = (i < N) ? deg[i] : 0;
  buf[threadIdx.x] = v;
  __syncthreads();
  int run = v;
  for (int off = 1; off < 1024; off <<= 1) {
    int t = ((int)threadIdx.x >= off) ? buf[threadIdx.x - off] : 0;
    __syncthreads();
    run += t;
    buf[threadIdx.x] = run;
    __syncthreads();
  }
  if (i < N) row_start[i] = run - v;  // exclusive, pre-block-offset
  if (threadIdx.x == 1023) bsum[blockIdx.x] = run;
}

__global__ void scan2_kernel(int* __restrict__ bsum, int* __restrict__ row_start,
                             int nb, int N) {
  int acc = 0;
  for (int b = 0; b < nb; ++b) {
    int t = bsum[b];
    bsum[b] = acc;
    acc += t;
  }
  row_start[N] = acc;
}

__global__ __launch_bounds__(1024) void scan3_kernel(int* __restrict__ row_start,
                                                     const int* __restrict__ bsum, int N) {
  int i = blockIdx.x * 1024 + (int)threadIdx.x;
  if (i < N) row_start[i] += bsum[blockIdx.x];
}

__global__ void fill_kernel(const int* __restrict__ ei, const int* __restrict__ row_start,
                            int* __restrict__ cursor, int* __restrict__ csr_src, int E) {
  int e = blockIdx.x * blockDim.x + threadIdx.x;
  if (e < E) {
    int d = ei[E + e];
    int slot = row_start[d] + atomicAdd(&cursor[d], 1);
    csr_src[slot] = ei[e];
  }
}

// ---- fused softmax + aggregation, single pass (no max-shift) ----------------
// one wave per dst node; softmax sum is wave-uniform per 16-lane head group.
__global__ __launch_bounds__(256) void gat_agg(
    const unsigned short* __restrict__ XHb, const float* __restrict__ a_src,
    const float* __restrict__ a_dst, const int* __restrict__ row_start,
    const int* __restrict__ csr_src, const float* __restrict__ bias,
    float* __restrict__ out, int N) {
  int wid = threadIdx.x >> 6;
  int lane = threadIdx.x & 63;
  int node = blockIdx.x * 4 + wid;
  if (node >= N) return;

  int h = lane >> 4;
  int c = lane << 2;
  float ad_h = a_dst[node * 4 + h];
  float as_h = a_src[node * 4 + h];
  float wself = __expf(LRELU(as_h + ad_h));

  int start = row_start[node];
  int end = row_start[node + 1];

  ushort4 sv = *reinterpret_cast<const ushort4*>(XHb + (size_t)node * 256 + c);
  float4 acc;
  acc.x = wself * bf2f(sv.x); acc.y = wself * bf2f(sv.y);
  acc.z = wself * bf2f(sv.z); acc.w = wself * bf2f(sv.w);
  float sw = wself;

  int p = start;
  for (; p + 4 <= end; p += 4) {
    int s0 = csr_src[p];
    int s1 = csr_src[p + 1];
    int s2 = csr_src[p + 2];
    int s3 = csr_src[p + 3];
    float a0 = a_src[s0 * 4 + h] + ad_h;
    float a1 = a_src[s1 * 4 + h] + ad_h;
    float a2 = a_src[s2 * 4 + h] + ad_h;
    float a3 = a_src[s3 * 4 + h] + ad_h;
    ushort4 u0 = *reinterpret_cast<const ushort4*>(XHb + (size_t)s0 * 256 + c);
    ushort4 u1 = *reinterpret_cast<const ushort4*>(XHb + (size_t)s1 * 256 + c);
    ushort4 u2 = *reinterpret_cast<const ushort4*>(XHb + (size_t)s2 * 256 + c);
    ushort4 u3 = *reinterpret_cast<const ushort4*>(XHb + (size_t)s3 * 256 + c);
    float w0 = __expf(LRELU(a0));
    float w1 = __expf(LRELU(a1));
    float w2 = __expf(LRELU(a2));
    float w3 = __expf(LRELU(a3));
    acc.x += w0 * bf2f(u0.x); acc.y += w0 * bf2f(u0.y);
    acc.z += w0 * bf2f(u0.z); acc.w += w0 * bf2f(u0.w);
    acc.x += w1 * bf2f(u1.x); acc.y += w1 * bf2f(u1.y);
    acc.z += w1 * bf2f(u1.z); acc.w += w1 * bf2f(u1.w);
    acc.x += w2 * bf2f(u2.x); acc.y += w2 * bf2f(u2.y);
    acc.z += w2 * bf2f(u2.z); acc.w += w2 * bf2f(u2.w);
    acc.x += w3 * bf2f(u3.x); acc.y += w3 * bf2f(u3.y);
    acc.z += w3 * bf2f(u3.z); acc.w += w3 * bf2f(u3.w);
    sw += w0 + w1 + w2 + w3;
  }
  for (; p < end; ++p) {
    int s0 = csr_src[p];
    float a0 = a_src[s0 * 4 + h] + ad_h;
    ushort4 u0 = *reinterpret_cast<const ushort4*>(XHb + (size_t)s0 * 256 + c);
    float w0 = __expf(LRELU(a0));
    acc.x += w0 * bf2f(u0.x); acc.y += w0 * bf2f(u0.y);
    acc.z += w0 * bf2f(u0.z); acc.w += w0 * bf2f(u0.w);
    sw += w0;
  }

  float inv = 1.0f / sw;
  float4 b = reinterpret_cast<const float4*>(bias)[lane];
  float4 o;
  o.x = acc.x * inv + b.x; o.y = acc.y * inv + b.y;
  o.z = acc.z * inv + b.z; o.w = acc.w * inv + b.w;
  *reinterpret_cast<float4*>(out + (size_t)node * 256 + c) = o;
}

extern "C" void kernel_launch(void* const* d_in, const int* in_sizes, int n_in,
                              void* d_out, int out_size, void* d_ws, size_t ws_size,
                              hipStream_t stream) {
  const float* x    = (const float*)d_in[0];
  const int*   ei   = (const int*)d_in[1];
  const float* Wm   = (const float*)d_in[2];
  const float* attS = (const float*)d_in[3];
  const float* attD = (const float*)d_in[4];
  const float* bias = (const float*)d_in[5];
  float* out = (float*)d_out;

  const int N = in_sizes[0] / 256;
  const int E = in_sizes[1] / 2;
  const int Mp = (N + 127) / 128 * 128;
  const int nb = (N + 1023) / 1024;

  char* w = (char*)d_ws;
  unsigned short* XHb = (unsigned short*)w;  w += (size_t)Mp * 256 * 2;
  unsigned short* Xb  = (unsigned short*)w;  w += (size_t)Mp * 256 * 2;
  unsigned short* Wtb = (unsigned short*)w;  w += (size_t)256 * 256 * 2;
  float* a_src = (float*)w;                  w += (size_t)N * 4 * 4;
  float* a_dst = (float*)w;                  w += (size_t)N * 4 * 4;
  int* deg = (int*)w;                        w += (size_t)N * 4;
  int* cursor = (int*)w;                     w += (size_t)N * 4;
  int* row_start = (int*)w;                  w += ((size_t)(N + 1) * 4 + 255) / 256 * 256;
  int* bsum = (int*)w;                       w += ((size_t)nb * 4 + 255) / 256 * 256;
  int* csr_src = (int*)w;                    w += (size_t)E * 4;

  convert_x<<<(Mp * 256 / 4 + 255) / 256, 256, 0, stream>>>(x, Xb, Mp * 256, N * 256);
  convert_wt<<<256, 256, 0, stream>>>(Wm, Wtb);

  dim3 ggrid(Mp / 128, 2);
  gemm_mfma<<<ggrid, 256, 0, stream>>>(Xb, Wtb, attS, attD, XHb, a_src, a_dst, Mp, N);

  hipMemsetAsync(deg, 0, (size_t)2 * N * 4, stream);  // deg + cursor (adjacent)
  count_kernel<<<(E + 255) / 256, 256, 0, stream>>>(ei, deg, E);
  scan1_kernel<<<nb, 1024, 0, stream>>>(deg, row_start, bsum, N);
  scan2_kernel<<<1, 1, 0, stream>>>(bsum, row_start, nb, N);
  scan3_kernel<<<nb, 1024, 0, stream>>>(row_start, bsum, N);
  fill_kernel<<<(E + 255) / 256, 256, 0, stream>>>(ei, row_start, cursor, csr_src, E);

  gat_agg<<<(N + 3) / 4, 256, 0, stream>>>(XHb, a_src, a_dst, row_start, csr_src,
                                           bias, out, N);
}